// Round 21
// baseline (88.175 us; speedup 1.0000x reference)
//
#include <hip/hip_runtime.h>

typedef __bf16 bf16;
typedef __bf16 bf16x4 __attribute__((ext_vector_type(4)));
typedef __bf16 bf16x8 __attribute__((ext_vector_type(8)));
typedef float f32x4 __attribute__((ext_vector_type(4)));

#define T_SEQ 2048
#define CDIM  1024
#define QKV_LD 3072
#define MEM   256

// global -> LDS direct DMA, 16B per lane. LDS dest is wave-uniform base + lane*16B.
#define GLOAD_LDS16(gp, lp) __builtin_amdgcn_global_load_lds( \
    (const __attribute__((address_space(1))) unsigned int*)(gp), \
    (__attribute__((address_space(3))) unsigned int*)(lp), 16, 0, 0)

#define BAR() do { __builtin_amdgcn_s_barrier(); asm volatile("" ::: "memory"); } while (0)

// ------------- fused prep (frozen R19) -------------
__global__ __launch_bounds__(256) void prep_kernel(const float* __restrict__ x,
                                                   const float* __restrict__ Wa,
                                                   const float* __restrict__ Wp,
                                                   bf16* __restrict__ xb,
                                                   bf16* __restrict__ WaT,
                                                   bf16* __restrict__ WpT) {
    const int bid = blockIdx.x;
    if (bid < 2048) {
        int i = bid * 256 + threadIdx.x;            // 8-elem chunk index
        float4 v0 = reinterpret_cast<const float4*>(x)[i * 2];
        float4 v1 = reinterpret_cast<const float4*>(x)[i * 2 + 1];
        bf16x8 o = { (bf16)v0.x, (bf16)v0.y, (bf16)v0.z, (bf16)v0.w,
                     (bf16)v1.x, (bf16)v1.y, (bf16)v1.z, (bf16)v1.w };
        reinterpret_cast<bf16x8*>(xb)[i] = o;
        return;
    }
    const float* W; bf16* Wt; int N, bx, by;
    if (bid < 2816) { W = Wa; Wt = WaT; N = 3072; int idx = bid - 2048; bx = idx % 48; by = idx / 48; }
    else            { W = Wp; Wt = WpT; N = 1024; int idx = bid - 2816; bx = idx % 16; by = idx / 16; }
    __shared__ float tile[64][65];
    const int n0 = bx * 64;
    const int k0 = by * 64;
    const int t  = threadIdx.x;
    const int tr = t >> 4;
    const int tc = (t & 15) * 4;
#pragma unroll
    for (int it = 0; it < 4; ++it) {
        int r = it * 16 + tr;
        float4 v = *reinterpret_cast<const float4*>(&W[(size_t)(k0 + r) * N + n0 + tc]);
        tile[r][tc + 0] = v.x; tile[r][tc + 1] = v.y;
        tile[r][tc + 2] = v.z; tile[r][tc + 3] = v.w;
    }
    __syncthreads();
#pragma unroll
    for (int it = 0; it < 4; ++it) {
        int n = it * 16 + tr;
        bf16x4 o;
#pragma unroll
        for (int j = 0; j < 4; ++j) o[j] = (bf16)tile[tc + j][n];
        *reinterpret_cast<bf16x4*>(&Wt[(size_t)(n0 + n) * 1024 + k0 + tc]) = o;
    }
}

// ------------- 128x192 GEMM (exact R16 structure — frozen, best verified) -------------
__global__ __launch_bounds__(512, 4) void gemm256_kernel(const bf16* __restrict__ A,
                                                         const bf16* __restrict__ Bt,
                                                         bf16* __restrict__ Cb,
                                                         bf16* __restrict__ Vt,
                                                         int M, int N, int K) {
    __shared__ bf16 lds[40960];          // 80 KiB: [0,16384) = A dbuf, [16384,40960) = B dbuf
#define SMA(bi, row) (lds + (((bi) * 128 + (row)) << 6))
#define SMB(bi, row) (lds + 16384 + (((bi) * 192 + (row)) << 6))
    const int t    = threadIdx.x;
    const int lane = t & 63;
    const int w    = t >> 6;
    const int wm   = (w >> 2) * 64;
    const int wn   = (w & 3) * 48;
    const int g    = lane >> 4;
    const int r    = lane & 15;

    const int xcd   = blockIdx.x & 7;
    const int local = blockIdx.x >> 3;
    const int mt = (xcd >> 1) * 8 + (local >> 3);
    const int nt = (xcd & 1) * 8 + (local & 7);
    const int m0 = mt * 128;
    const int n0 = nt * 192;

    const bf16* Ab = A  + (size_t)m0 * K;
    const bf16* Bb = Bt + (size_t)n0 * K;
    const int NT = K >> 6;

#define STAGE_A(bi, u, kt) do { \
        const bf16* _s = Ab + (size_t)((u) * 64 + w * 8 + (lane >> 3)) * K \
                         + (kt) * 64 + ((lane & 7) ^ (lane >> 3)) * 8; \
        GLOAD_LDS16(_s, SMA(bi, (u) * 64 + w * 8)); \
    } while (0)
#define STAGE_B(bi, u, kt) do { \
        const bf16* _s = Bb + (size_t)((u) * 64 + w * 8 + (lane >> 3)) * K \
                         + (kt) * 64 + ((lane & 7) ^ (lane >> 3)) * 8; \
        GLOAD_LDS16(_s, SMB(bi, (u) * 64 + w * 8)); \
    } while (0)

    const int ch0 = ((g     ) ^ (r & 7)) * 8;
    const int ch1 = ((g ^ 4) ^ (r & 7)) * 8;

    const f32x4 zero4 = {0.f, 0.f, 0.f, 0.f};
    f32x4 acc[4][3];
#pragma unroll
    for (int i = 0; i < 4; ++i)
#pragma unroll
        for (int j = 0; j < 3; ++j) acc[i][j] = zero4;

    bf16x8 afr[4][2], bfrA[2][2], bfrB[1][2];

#define MGRP(BF, FNB, NF) do { \
    __builtin_amdgcn_s_setprio(1); \
    _Pragma("unroll") \
    for (int fm2 = 0; fm2 < 4; ++fm2) \
    _Pragma("unroll") \
    for (int fn2 = 0; fn2 < (NF); ++fn2) \
    _Pragma("unroll") \
    for (int kh = 0; kh < 2; ++kh) \
        acc[fm2][(FNB)+fn2] = __builtin_amdgcn_mfma_f32_16x16x32_bf16( \
            afr[fm2][kh], BF[fn2][kh], acc[fm2][(FNB)+fn2], 0, 0, 0); \
    __builtin_amdgcn_s_setprio(0); } while (0)

    STAGE_A(0, 0, 0); STAGE_A(0, 1, 0);
    STAGE_B(0, 0, 0); STAGE_B(0, 1, 0); STAGE_B(0, 2, 0);
    asm volatile("s_waitcnt vmcnt(0)" ::: "memory");
    __builtin_amdgcn_sched_barrier(0);
    BAR();

    for (int kt = 0; kt < NT; ++kt) {
        const int cur = kt & 1, nxt = cur ^ 1;
#pragma unroll
        for (int i = 0; i < 4; ++i) {
            afr[i][0] = *reinterpret_cast<const bf16x8*>(SMA(cur, wm + i * 16 + r) + ch0);
            afr[i][1] = *reinterpret_cast<const bf16x8*>(SMA(cur, wm + i * 16 + r) + ch1);
        }
#pragma unroll
        for (int fn = 0; fn < 2; ++fn) {
            bfrA[fn][0] = *reinterpret_cast<const bf16x8*>(SMB(cur, wn + fn * 16 + r) + ch0);
            bfrA[fn][1] = *reinterpret_cast<const bf16x8*>(SMB(cur, wn + fn * 16 + r) + ch1);
        }
        bfrB[0][0] = *reinterpret_cast<const bf16x8*>(SMB(cur, wn + 32 + r) + ch0);
        bfrB[0][1] = *reinterpret_cast<const bf16x8*>(SMB(cur, wn + 32 + r) + ch1);

        if (kt + 1 < NT) {
            STAGE_A(nxt, 0, kt + 1); STAGE_A(nxt, 1, kt + 1);
            STAGE_B(nxt, 0, kt + 1); STAGE_B(nxt, 1, kt + 1); STAGE_B(nxt, 2, kt + 1);
        }

        MGRP(bfrA, 0, 2);
        MGRP(bfrB, 2, 1);

        asm volatile("s_waitcnt vmcnt(0)" ::: "memory");
        __builtin_amdgcn_sched_barrier(0);
        BAR();
    }

    bf16* stage = lds + (size_t)w * (48 * 72);
#pragma unroll
    for (int fm = 0; fm < 4; ++fm)
#pragma unroll
        for (int fn = 0; fn < 3; ++fn) {
            const int col  = n0 + wn + fn * 16 + r;
            const int row0 = m0 + wm + fm * 16 + g * 4;
            if (col < 2 * CDIM) {
#pragma unroll
                for (int e = 0; e < 4; ++e)
                    Cb[(size_t)(row0 + e) * N + col] = (bf16)acc[fm][fn][e];
            } else {
                const int dl = fn * 16 + r;
                const int tl = fm * 16 + g * 4;
#pragma unroll
                for (int e = 0; e < 4; ++e)
                    stage[dl * 72 + tl + e] = (bf16)acc[fm][fn][e];
            }
        }
    if (n0 + wn + 47 >= 2 * CDIM) {
        if (lane < 48 && (n0 + wn + lane) >= 2 * CDIM) {
            const int hd = n0 + wn + lane - 2 * CDIM;
            const int bb = m0 >> 11;
            const int tt = (m0 & (T_SEQ - 1)) + wm;
            bf16* dst = &Vt[((size_t)(bb * 16 + (hd >> 6)) * 64 + (hd & 63)) * T_SEQ + tt];
            const bf16* srcl = stage + lane * 72;
#pragma unroll
            for (int jj = 0; jj < 8; ++jj)
                reinterpret_cast<bf16x8*>(dst)[jj] = reinterpret_cast<const bf16x8*>(srcl)[jj];
        }
    }
#undef STAGE_A
#undef STAGE_B
#undef MGRP
#undef SMA
#undef SMB
}

// ------------- proj GEMM: race-free t+1 double-buffer (frozen R20) -------------
__global__ __launch_bounds__(256) void proj_kernel(const bf16* __restrict__ A,
                                                   const bf16* __restrict__ Bt,
                                                   float* __restrict__ Cf,
                                                   int M, int N, int K) {
    __shared__ bf16 As[2][128 * 32];
    __shared__ bf16 Bs[2][64 * 32];
    const int t    = threadIdx.x;
    const int lane = t & 63;
    const int w    = t >> 6;
    const int wm   = (w >> 1) * 64;
    const int wn   = (w & 1) * 32;
    const int g    = lane >> 4;
    const int r    = lane & 15;
    const int m0   = blockIdx.y * 128;
    const int n0   = blockIdx.x * 64;

    const bf16* Ab = A  + (size_t)m0 * K;
    const bf16* Bb = Bt + (size_t)n0 * K;
    const bf16* Ag0 = Ab + (size_t)(w * 32 + (lane >> 2)) * K + (lane & 3) * 8;
    const bf16* Ag1 = Ab + (size_t)(w * 32 + 16 + (lane >> 2)) * K + (lane & 3) * 8;
    const bf16* Bg0 = Bb + (size_t)(w * 16 + (lane >> 2)) * K + (lane & 3) * 8;

    const int aoff0 = (w * 32) * 32;
    const int aoff1 = (w * 32 + 16) * 32;
    const int boff0 = (w * 16) * 32;

    const f32x4 zero4 = {0.f, 0.f, 0.f, 0.f};
    f32x4 acc[4][2];
#pragma unroll
    for (int i = 0; i < 4; ++i)
#pragma unroll
        for (int j = 0; j < 2; ++j) acc[i][j] = zero4;

    const int NT = K >> 5;               // K-steps of 32

    GLOAD_LDS16(Ag0, &As[0][aoff0]);
    GLOAD_LDS16(Ag1, &As[0][aoff1]);
    GLOAD_LDS16(Bg0, &Bs[0][boff0]);
    asm volatile("s_waitcnt vmcnt(0)" ::: "memory");
    __builtin_amdgcn_sched_barrier(0);
    BAR();

    for (int kt = 0; kt < NT; ++kt) {
        const int cur = kt & 1, nxt = cur ^ 1;
        bf16x8 af[4], bfr[2];
#pragma unroll
        for (int i = 0; i < 4; ++i)
            af[i]  = *reinterpret_cast<const bf16x8*>(&As[cur][(wm + i * 16 + r) * 32 + g * 8]);
#pragma unroll
        for (int j = 0; j < 2; ++j)
            bfr[j] = *reinterpret_cast<const bf16x8*>(&Bs[cur][(wn + j * 16 + r) * 32 + g * 8]);

        if (kt + 1 < NT) {
            const int k1 = (kt + 1) * 32;
            GLOAD_LDS16(Ag0 + k1, &As[nxt][aoff0]);
            GLOAD_LDS16(Ag1 + k1, &As[nxt][aoff1]);
            GLOAD_LDS16(Bg0 + k1, &Bs[nxt][boff0]);
        }

#pragma unroll
        for (int i = 0; i < 4; ++i)
#pragma unroll
            for (int j = 0; j < 2; ++j)
                acc[i][j] = __builtin_amdgcn_mfma_f32_16x16x32_bf16(af[i], bfr[j], acc[i][j], 0, 0, 0);

        asm volatile("s_waitcnt vmcnt(0)" ::: "memory");
        __builtin_amdgcn_sched_barrier(0);
        BAR();
    }

#pragma unroll
    for (int i = 0; i < 4; ++i)
#pragma unroll
        for (int j = 0; j < 2; ++j)
#pragma unroll
            for (int e = 0; e < 4; ++e) {
                int row = m0 + wm + i * 16 + g * 4 + e;
                int col = n0 + wn + j * 16 + r;
                Cf[(size_t)row * N + col] = acc[i][j][e];
            }
}

// ------------- banded flash attention v5 + T13 defer-max (isolated; R12-proven path) -------------
__global__ __launch_bounds__(512) void attn_kernel(const bf16* __restrict__ qkv,
                                                   const bf16* __restrict__ Vt,
                                                   bf16* __restrict__ y) {
    __shared__ bf16 vtl[64 * 384];
    const int bid  = blockIdx.x;
    const int bh   = bid >> 4;
    const int qblk = bid & 15;
    const int b = bh >> 4, h = bh & 15;
    const int qb0 = qblk * 128;
    const int wlo = qb0 - 256;
    const int wv   = threadIdx.x >> 6;
    const int lane = threadIdx.x & 63;
    const int g = lane >> 4, c = lane & 15;
    const int q0 = qb0 + wv * 16;
    const int q = q0 + c;
    const float NEG_INF = -__builtin_inff();

    const bf16* base = qkv + (size_t)b * T_SEQ * QKV_LD;
    const bf16* Qb = base + h * 64;
    const bf16* Kb = base + CDIM + h * 64;
    const bf16* Vtb = Vt + (size_t)(b * 16 + h) * 64 * T_SEQ;

#pragma unroll
    for (int i = 0; i < 6; ++i) {
        const int Lb = (wv * 6 + i) * 1024 + lane * 16;
        const int d   = Lb / 768;
        const int c16 = (Lb % 768) >> 4;
        int koff = ((2 * c16) ^ (d & 14)) << 2;
        int gk = wlo + koff;
        gk = gk < 0 ? 0 : gk;
        GLOAD_LDS16(Vtb + (size_t)d * T_SEQ + gk, vtl + (wv * 6 + i) * 512);
    }

    const bf16x8 qf0 = *reinterpret_cast<const bf16x8*>(Qb + (size_t)q * QKV_LD + g * 8);
    const bf16x8 qf1 = *reinterpret_cast<const bf16x8*>(Qb + (size_t)q * QKV_LD + 32 + g * 8);

    __syncthreads();

    const f32x4 zero4 = {0.f, 0.f, 0.f, 0.f};
    f32x4 o[4];
#pragma unroll
    for (int cb = 0; cb < 4; ++cb) o[cb] = zero4;
    float m_run = NEG_INF, l_run = 0.f;

#define LOAD_K(J0, K00, K01, K10, K11) do { \
        const int _kr0 = (J0) + c; \
        int _kr1 = (J0) + 16 + c; _kr1 = _kr1 < T_SEQ ? _kr1 : T_SEQ - 1; \
        K00 = *reinterpret_cast<const bf16x8*>(Kb + (size_t)_kr0 * QKV_LD + g * 8); \
        K01 = *reinterpret_cast<const bf16x8*>(Kb + (size_t)_kr0 * QKV_LD + 32 + g * 8); \
        K10 = *reinterpret_cast<const bf16x8*>(Kb + (size_t)_kr1 * QKV_LD + g * 8); \
        K11 = *reinterpret_cast<const bf16x8*>(Kb + (size_t)_kr1 * QKV_LD + 32 + g * 8); \
    } while (0)

    const int jstart = (q0 - MEM > 0) ? (q0 - MEM) : 0;
    bf16x8 kc00, kc01, kc10, kc11;
    LOAD_K(jstart, kc00, kc01, kc10, kc11);

    for (int j0 = jstart; j0 < q0 + 16; j0 += 32) {
        bf16x8 kn00, kn01, kn10, kn11;
        const bool more = (j0 + 32 < q0 + 16);
        if (more) LOAD_K(j0 + 32, kn00, kn01, kn10, kn11);

        f32x4 s0 = __builtin_amdgcn_mfma_f32_16x16x32_bf16(kc00, qf0, zero4, 0, 0, 0);
        s0 = __builtin_amdgcn_mfma_f32_16x16x32_bf16(kc01, qf1, s0, 0, 0, 0);
        f32x4 s1 = __builtin_amdgcn_mfma_f32_16x16x32_bf16(kc10, qf0, zero4, 0, 0, 0);
        s1 = __builtin_amdgcn_mfma_f32_16x16x32_bf16(kc11, qf1, s1, 0, 0, 0);

        float mt = NEG_INF;
#pragma unroll
        for (int e = 0; e < 4; ++e) {
            int k0i = j0 + 4 * g + e;
            int k1i = k0i + 16;
            float v0 = (k0i <= q && k0i >= q - MEM) ? s0[e] * 0.125f : NEG_INF;
            float v1 = (k1i <= q && k1i >= q - MEM) ? s1[e] * 0.125f : NEG_INF;
            s0[e] = v0; s1[e] = v1;
            mt = fmaxf(mt, fmaxf(v0, v1));
        }
        mt = fmaxf(mt, __shfl_xor(mt, 16, 64));
        mt = fmaxf(mt, __shfl_xor(mt, 32, 64));

        // --- T13 defer-max: rescale only when the tile max grew past m_run + 8.
        //     P bounded by e^8; f32 accumulators; the scale divides out in the epilogue. ---
        if (!__all(mt <= m_run + 8.f)) {
            const float mnew = fmaxf(m_run, mt);
            const float corr = __expf(m_run - mnew);   // lane-local (q = c); first tile: 0
#pragma unroll
            for (int cb = 0; cb < 4; ++cb) {
                o[cb][0] *= corr; o[cb][1] *= corr; o[cb][2] *= corr; o[cb][3] *= corr;
            }
            l_run *= corr;
            m_run = mnew;
        }

        float ps = 0.f;
        bf16x8 pav;
#pragma unroll
        for (int e = 0; e < 4; ++e) {
            float e0 = __expf(s0[e] - m_run);
            float e1 = __expf(s1[e] - m_run);
            ps += e0 + e1;
            pav[e]     = (bf16)e0;
            pav[4 + e] = (bf16)e1;
        }
        ps += __shfl_xor(ps, 16, 64);
        ps += __shfl_xor(ps, 32, 64);
        l_run += ps;

        const int jrel = j0 - wlo;
        const int c8a = (jrel + 4 * g) >> 2;
        const int c8b = (c8a + 4 > 95) ? 95 : (c8a + 4);
#pragma unroll
        for (int cb = 0; cb < 4; ++cb) {
            const int d = cb * 16 + c;
            const int xx = d & 14;
            const bf16* vrow = vtl + d * 384;
            bf16x4 va  = *reinterpret_cast<const bf16x4*>(vrow + ((c8a ^ xx) << 2));
            bf16x4 vb2 = *reinterpret_cast<const bf16x4*>(vrow + ((c8b ^ xx) << 2));
            bf16x8 vf = { va[0], va[1], va[2], va[3], vb2[0], vb2[1], vb2[2], vb2[3] };
            o[cb] = __builtin_amdgcn_mfma_f32_16x16x32_bf16(vf, pav, o[cb], 0, 0, 0);
        }

        if (more) { kc00 = kn00; kc01 = kn01; kc10 = kn10; kc11 = kn11; }
    }
#undef LOAD_K

    const float linv = 1.0f / l_run;
    bf16* yr = y + (size_t)(b * T_SEQ + q) * CDIM + h * 64 + 4 * g;
#pragma unroll
    for (int cb = 0; cb < 4; ++cb) {
        bf16x4 ov = { (bf16)(o[cb][0] * linv), (bf16)(o[cb][1] * linv),
                      (bf16)(o[cb][2] * linv), (bf16)(o[cb][3] * linv) };
        *reinterpret_cast<bf16x4*>(yr + cb * 16) = ov;
    }
}

// ---------------- launch ----------------
extern "C" void kernel_launch(void* const* d_in, const int* in_sizes, int n_in,
                              void* d_out, int out_size, void* d_ws, size_t ws_size,
                              hipStream_t stream) {
    const float* x      = (const float*)d_in[0];
    const float* W_attn = (const float*)d_in[1];
    const float* W_proj = (const float*)d_in[2];
    float* out = (float*)d_out;

    char* ws = (char*)d_ws;
    bf16* xb   = (bf16*)(ws);                  //  4096x1024 bf16 =  8 MiB
    bf16* WaT  = (bf16*)(ws + 8388608);        //  3072x1024 bf16 =  6 MiB
    bf16* WpT  = (bf16*)(ws + 14680064);       //  1024x1024 bf16 =  2 MiB
    bf16* qkv  = (bf16*)(ws + 16777216);       //  4096x3072 bf16 = 24 MiB (V third unused)
    bf16* yatt = (bf16*)(ws + 41943040);       //  4096x1024 bf16 =  8 MiB
    bf16* Vt   = (bf16*)(ws + 50331648);       //  2x16x64x2048 bf16 = 8 MiB

    prep_kernel<<<3072, 256, 0, stream>>>(x, W_attn, W_proj, xb, WaT, WpT);
    gemm256_kernel<<<512, 512, 0, stream>>>(xb, WaT, qkv, Vt, 4096, 3072, 1024);
    attn_kernel<<<512, 512, 0, stream>>>(qkv, Vt, yatt);
    proj_kernel<<<dim3(16, 32), 256, 0, stream>>>(yatt, WpT, out, 4096, 1024, 1024);
}

// Round 22
// 88.088 us; speedup vs baseline: 1.0010x; 1.0010x over previous
//
#include <hip/hip_runtime.h>

typedef __bf16 bf16;
typedef __bf16 bf16x4 __attribute__((ext_vector_type(4)));
typedef __bf16 bf16x8 __attribute__((ext_vector_type(8)));
typedef float f32x4 __attribute__((ext_vector_type(4)));

#define T_SEQ 2048
#define CDIM  1024
#define QKV_LD 3072
#define MEM   256

// global -> LDS direct DMA, 16B per lane. LDS dest is wave-uniform base + lane*16B.
#define GLOAD_LDS16(gp, lp) __builtin_amdgcn_global_load_lds( \
    (const __attribute__((address_space(1))) unsigned int*)(gp), \
    (__attribute__((address_space(3))) unsigned int*)(lp), 16, 0, 0)

#define BAR() do { __builtin_amdgcn_s_barrier(); asm volatile("" ::: "memory"); } while (0)

// ------------- fused prep (frozen R19) -------------
__global__ __launch_bounds__(256) void prep_kernel(const float* __restrict__ x,
                                                   const float* __restrict__ Wa,
                                                   const float* __restrict__ Wp,
                                                   bf16* __restrict__ xb,
                                                   bf16* __restrict__ WaT,
                                                   bf16* __restrict__ WpT) {
    const int bid = blockIdx.x;
    if (bid < 2048) {
        int i = bid * 256 + threadIdx.x;            // 8-elem chunk index
        float4 v0 = reinterpret_cast<const float4*>(x)[i * 2];
        float4 v1 = reinterpret_cast<const float4*>(x)[i * 2 + 1];
        bf16x8 o = { (bf16)v0.x, (bf16)v0.y, (bf16)v0.z, (bf16)v0.w,
                     (bf16)v1.x, (bf16)v1.y, (bf16)v1.z, (bf16)v1.w };
        reinterpret_cast<bf16x8*>(xb)[i] = o;
        return;
    }
    const float* W; bf16* Wt; int N, bx, by;
    if (bid < 2816) { W = Wa; Wt = WaT; N = 3072; int idx = bid - 2048; bx = idx % 48; by = idx / 48; }
    else            { W = Wp; Wt = WpT; N = 1024; int idx = bid - 2816; bx = idx % 16; by = idx / 16; }
    __shared__ float tile[64][65];
    const int n0 = bx * 64;
    const int k0 = by * 64;
    const int t  = threadIdx.x;
    const int tr = t >> 4;
    const int tc = (t & 15) * 4;
#pragma unroll
    for (int it = 0; it < 4; ++it) {
        int r = it * 16 + tr;
        float4 v = *reinterpret_cast<const float4*>(&W[(size_t)(k0 + r) * N + n0 + tc]);
        tile[r][tc + 0] = v.x; tile[r][tc + 1] = v.y;
        tile[r][tc + 2] = v.z; tile[r][tc + 3] = v.w;
    }
    __syncthreads();
#pragma unroll
    for (int it = 0; it < 4; ++it) {
        int n = it * 16 + tr;
        bf16x4 o;
#pragma unroll
        for (int j = 0; j < 4; ++j) o[j] = (bf16)tile[tc + j][n];
        *reinterpret_cast<bf16x4*>(&Wt[(size_t)(n0 + n) * 1024 + k0 + tc]) = o;
    }
}

// ------------- 128x192 GEMM (exact R16 structure — frozen, best verified) -------------
__global__ __launch_bounds__(512, 4) void gemm256_kernel(const bf16* __restrict__ A,
                                                         const bf16* __restrict__ Bt,
                                                         bf16* __restrict__ Cb,
                                                         bf16* __restrict__ Vt,
                                                         int M, int N, int K) {
    __shared__ bf16 lds[40960];          // 80 KiB: [0,16384) = A dbuf, [16384,40960) = B dbuf
#define SMA(bi, row) (lds + (((bi) * 128 + (row)) << 6))
#define SMB(bi, row) (lds + 16384 + (((bi) * 192 + (row)) << 6))
    const int t    = threadIdx.x;
    const int lane = t & 63;
    const int w    = t >> 6;
    const int wm   = (w >> 2) * 64;
    const int wn   = (w & 3) * 48;
    const int g    = lane >> 4;
    const int r    = lane & 15;

    const int xcd   = blockIdx.x & 7;
    const int local = blockIdx.x >> 3;
    const int mt = (xcd >> 1) * 8 + (local >> 3);
    const int nt = (xcd & 1) * 8 + (local & 7);
    const int m0 = mt * 128;
    const int n0 = nt * 192;

    const bf16* Ab = A  + (size_t)m0 * K;
    const bf16* Bb = Bt + (size_t)n0 * K;
    const int NT = K >> 6;

#define STAGE_A(bi, u, kt) do { \
        const bf16* _s = Ab + (size_t)((u) * 64 + w * 8 + (lane >> 3)) * K \
                         + (kt) * 64 + ((lane & 7) ^ (lane >> 3)) * 8; \
        GLOAD_LDS16(_s, SMA(bi, (u) * 64 + w * 8)); \
    } while (0)
#define STAGE_B(bi, u, kt) do { \
        const bf16* _s = Bb + (size_t)((u) * 64 + w * 8 + (lane >> 3)) * K \
                         + (kt) * 64 + ((lane & 7) ^ (lane >> 3)) * 8; \
        GLOAD_LDS16(_s, SMB(bi, (u) * 64 + w * 8)); \
    } while (0)

    const int ch0 = ((g     ) ^ (r & 7)) * 8;
    const int ch1 = ((g ^ 4) ^ (r & 7)) * 8;

    const f32x4 zero4 = {0.f, 0.f, 0.f, 0.f};
    f32x4 acc[4][3];
#pragma unroll
    for (int i = 0; i < 4; ++i)
#pragma unroll
        for (int j = 0; j < 3; ++j) acc[i][j] = zero4;

    bf16x8 afr[4][2], bfrA[2][2], bfrB[1][2];

#define MGRP(BF, FNB, NF) do { \
    __builtin_amdgcn_s_setprio(1); \
    _Pragma("unroll") \
    for (int fm2 = 0; fm2 < 4; ++fm2) \
    _Pragma("unroll") \
    for (int fn2 = 0; fn2 < (NF); ++fn2) \
    _Pragma("unroll") \
    for (int kh = 0; kh < 2; ++kh) \
        acc[fm2][(FNB)+fn2] = __builtin_amdgcn_mfma_f32_16x16x32_bf16( \
            afr[fm2][kh], BF[fn2][kh], acc[fm2][(FNB)+fn2], 0, 0, 0); \
    __builtin_amdgcn_s_setprio(0); } while (0)

    STAGE_A(0, 0, 0); STAGE_A(0, 1, 0);
    STAGE_B(0, 0, 0); STAGE_B(0, 1, 0); STAGE_B(0, 2, 0);
    asm volatile("s_waitcnt vmcnt(0)" ::: "memory");
    __builtin_amdgcn_sched_barrier(0);
    BAR();

    for (int kt = 0; kt < NT; ++kt) {
        const int cur = kt & 1, nxt = cur ^ 1;
#pragma unroll
        for (int i = 0; i < 4; ++i) {
            afr[i][0] = *reinterpret_cast<const bf16x8*>(SMA(cur, wm + i * 16 + r) + ch0);
            afr[i][1] = *reinterpret_cast<const bf16x8*>(SMA(cur, wm + i * 16 + r) + ch1);
        }
#pragma unroll
        for (int fn = 0; fn < 2; ++fn) {
            bfrA[fn][0] = *reinterpret_cast<const bf16x8*>(SMB(cur, wn + fn * 16 + r) + ch0);
            bfrA[fn][1] = *reinterpret_cast<const bf16x8*>(SMB(cur, wn + fn * 16 + r) + ch1);
        }
        bfrB[0][0] = *reinterpret_cast<const bf16x8*>(SMB(cur, wn + 32 + r) + ch0);
        bfrB[0][1] = *reinterpret_cast<const bf16x8*>(SMB(cur, wn + 32 + r) + ch1);

        if (kt + 1 < NT) {
            STAGE_A(nxt, 0, kt + 1); STAGE_A(nxt, 1, kt + 1);
            STAGE_B(nxt, 0, kt + 1); STAGE_B(nxt, 1, kt + 1); STAGE_B(nxt, 2, kt + 1);
        }

        MGRP(bfrA, 0, 2);
        MGRP(bfrB, 2, 1);

        asm volatile("s_waitcnt vmcnt(0)" ::: "memory");
        __builtin_amdgcn_sched_barrier(0);
        BAR();
    }

    bf16* stage = lds + (size_t)w * (48 * 72);
#pragma unroll
    for (int fm = 0; fm < 4; ++fm)
#pragma unroll
        for (int fn = 0; fn < 3; ++fn) {
            const int col  = n0 + wn + fn * 16 + r;
            const int row0 = m0 + wm + fm * 16 + g * 4;
            if (col < 2 * CDIM) {
#pragma unroll
                for (int e = 0; e < 4; ++e)
                    Cb[(size_t)(row0 + e) * N + col] = (bf16)acc[fm][fn][e];
            } else {
                const int dl = fn * 16 + r;
                const int tl = fm * 16 + g * 4;
#pragma unroll
                for (int e = 0; e < 4; ++e)
                    stage[dl * 72 + tl + e] = (bf16)acc[fm][fn][e];
            }
        }
    if (n0 + wn + 47 >= 2 * CDIM) {
        if (lane < 48 && (n0 + wn + lane) >= 2 * CDIM) {
            const int hd = n0 + wn + lane - 2 * CDIM;
            const int bb = m0 >> 11;
            const int tt = (m0 & (T_SEQ - 1)) + wm;
            bf16* dst = &Vt[((size_t)(bb * 16 + (hd >> 6)) * 64 + (hd & 63)) * T_SEQ + tt];
            const bf16* srcl = stage + lane * 72;
#pragma unroll
            for (int jj = 0; jj < 8; ++jj)
                reinterpret_cast<bf16x8*>(dst)[jj] = reinterpret_cast<const bf16x8*>(srcl)[jj];
        }
    }
#undef STAGE_A
#undef STAGE_B
#undef MGRP
#undef SMA
#undef SMB
}

// ------------- proj GEMM: race-free t+1 double-buffer (frozen R20) -------------
__global__ __launch_bounds__(256) void proj_kernel(const bf16* __restrict__ A,
                                                   const bf16* __restrict__ Bt,
                                                   float* __restrict__ Cf,
                                                   int M, int N, int K) {
    __shared__ bf16 As[2][128 * 32];
    __shared__ bf16 Bs[2][64 * 32];
    const int t    = threadIdx.x;
    const int lane = t & 63;
    const int w    = t >> 6;
    const int wm   = (w >> 1) * 64;
    const int wn   = (w & 1) * 32;
    const int g    = lane >> 4;
    const int r    = lane & 15;
    const int m0   = blockIdx.y * 128;
    const int n0   = blockIdx.x * 64;

    const bf16* Ab = A  + (size_t)m0 * K;
    const bf16* Bb = Bt + (size_t)n0 * K;
    const bf16* Ag0 = Ab + (size_t)(w * 32 + (lane >> 2)) * K + (lane & 3) * 8;
    const bf16* Ag1 = Ab + (size_t)(w * 32 + 16 + (lane >> 2)) * K + (lane & 3) * 8;
    const bf16* Bg0 = Bb + (size_t)(w * 16 + (lane >> 2)) * K + (lane & 3) * 8;

    const int aoff0 = (w * 32) * 32;
    const int aoff1 = (w * 32 + 16) * 32;
    const int boff0 = (w * 16) * 32;

    const f32x4 zero4 = {0.f, 0.f, 0.f, 0.f};
    f32x4 acc[4][2];
#pragma unroll
    for (int i = 0; i < 4; ++i)
#pragma unroll
        for (int j = 0; j < 2; ++j) acc[i][j] = zero4;

    const int NT = K >> 5;               // K-steps of 32

    GLOAD_LDS16(Ag0, &As[0][aoff0]);
    GLOAD_LDS16(Ag1, &As[0][aoff1]);
    GLOAD_LDS16(Bg0, &Bs[0][boff0]);
    asm volatile("s_waitcnt vmcnt(0)" ::: "memory");
    __builtin_amdgcn_sched_barrier(0);
    BAR();

    for (int kt = 0; kt < NT; ++kt) {
        const int cur = kt & 1, nxt = cur ^ 1;
        bf16x8 af[4], bfr[2];
#pragma unroll
        for (int i = 0; i < 4; ++i)
            af[i]  = *reinterpret_cast<const bf16x8*>(&As[cur][(wm + i * 16 + r) * 32 + g * 8]);
#pragma unroll
        for (int j = 0; j < 2; ++j)
            bfr[j] = *reinterpret_cast<const bf16x8*>(&Bs[cur][(wn + j * 16 + r) * 32 + g * 8]);

        if (kt + 1 < NT) {
            const int k1 = (kt + 1) * 32;
            GLOAD_LDS16(Ag0 + k1, &As[nxt][aoff0]);
            GLOAD_LDS16(Ag1 + k1, &As[nxt][aoff1]);
            GLOAD_LDS16(Bg0 + k1, &Bs[nxt][boff0]);
        }

#pragma unroll
        for (int i = 0; i < 4; ++i)
#pragma unroll
            for (int j = 0; j < 2; ++j)
                acc[i][j] = __builtin_amdgcn_mfma_f32_16x16x32_bf16(af[i], bfr[j], acc[i][j], 0, 0, 0);

        asm volatile("s_waitcnt vmcnt(0)" ::: "memory");
        __builtin_amdgcn_sched_barrier(0);
        BAR();
    }

#pragma unroll
    for (int i = 0; i < 4; ++i)
#pragma unroll
        for (int j = 0; j < 2; ++j)
#pragma unroll
            for (int e = 0; e < 4; ++e) {
                int row = m0 + wm + i * 16 + g * 4 + e;
                int col = n0 + wn + j * 16 + r;
                Cf[(size_t)row * N + col] = acc[i][j][e];
            }
}

// ------------- banded flash attention v5 + T13 defer-max (frozen R21) -------------
__global__ __launch_bounds__(512) void attn_kernel(const bf16* __restrict__ qkv,
                                                   const bf16* __restrict__ Vt,
                                                   bf16* __restrict__ y) {
    __shared__ bf16 vtl[64 * 384];
    const int bid  = blockIdx.x;
    const int bh   = bid >> 4;
    const int qblk = bid & 15;
    const int b = bh >> 4, h = bh & 15;
    const int qb0 = qblk * 128;
    const int wlo = qb0 - 256;
    const int wv   = threadIdx.x >> 6;
    const int lane = threadIdx.x & 63;
    const int g = lane >> 4, c = lane & 15;
    const int q0 = qb0 + wv * 16;
    const int q = q0 + c;
    const float NEG_INF = -__builtin_inff();

    const bf16* base = qkv + (size_t)b * T_SEQ * QKV_LD;
    const bf16* Qb = base + h * 64;
    const bf16* Kb = base + CDIM + h * 64;
    const bf16* Vtb = Vt + (size_t)(b * 16 + h) * 64 * T_SEQ;

#pragma unroll
    for (int i = 0; i < 6; ++i) {
        const int Lb = (wv * 6 + i) * 1024 + lane * 16;
        const int d   = Lb / 768;
        const int c16 = (Lb % 768) >> 4;
        int koff = ((2 * c16) ^ (d & 14)) << 2;
        int gk = wlo + koff;
        gk = gk < 0 ? 0 : gk;
        GLOAD_LDS16(Vtb + (size_t)d * T_SEQ + gk, vtl + (wv * 6 + i) * 512);
    }

    const bf16x8 qf0 = *reinterpret_cast<const bf16x8*>(Qb + (size_t)q * QKV_LD + g * 8);
    const bf16x8 qf1 = *reinterpret_cast<const bf16x8*>(Qb + (size_t)q * QKV_LD + 32 + g * 8);

    __syncthreads();

    const f32x4 zero4 = {0.f, 0.f, 0.f, 0.f};
    f32x4 o[4];
#pragma unroll
    for (int cb = 0; cb < 4; ++cb) o[cb] = zero4;
    float m_run = NEG_INF, l_run = 0.f;

#define LOAD_K(J0, K00, K01, K10, K11) do { \
        const int _kr0 = (J0) + c; \
        int _kr1 = (J0) + 16 + c; _kr1 = _kr1 < T_SEQ ? _kr1 : T_SEQ - 1; \
        K00 = *reinterpret_cast<const bf16x8*>(Kb + (size_t)_kr0 * QKV_LD + g * 8); \
        K01 = *reinterpret_cast<const bf16x8*>(Kb + (size_t)_kr0 * QKV_LD + 32 + g * 8); \
        K10 = *reinterpret_cast<const bf16x8*>(Kb + (size_t)_kr1 * QKV_LD + g * 8); \
        K11 = *reinterpret_cast<const bf16x8*>(Kb + (size_t)_kr1 * QKV_LD + 32 + g * 8); \
    } while (0)

    const int jstart = (q0 - MEM > 0) ? (q0 - MEM) : 0;
    bf16x8 kc00, kc01, kc10, kc11;
    LOAD_K(jstart, kc00, kc01, kc10, kc11);

    for (int j0 = jstart; j0 < q0 + 16; j0 += 32) {
        bf16x8 kn00, kn01, kn10, kn11;
        const bool more = (j0 + 32 < q0 + 16);
        if (more) LOAD_K(j0 + 32, kn00, kn01, kn10, kn11);

        f32x4 s0 = __builtin_amdgcn_mfma_f32_16x16x32_bf16(kc00, qf0, zero4, 0, 0, 0);
        s0 = __builtin_amdgcn_mfma_f32_16x16x32_bf16(kc01, qf1, s0, 0, 0, 0);
        f32x4 s1 = __builtin_amdgcn_mfma_f32_16x16x32_bf16(kc10, qf0, zero4, 0, 0, 0);
        s1 = __builtin_amdgcn_mfma_f32_16x16x32_bf16(kc11, qf1, s1, 0, 0, 0);

        float mt = NEG_INF;
#pragma unroll
        for (int e = 0; e < 4; ++e) {
            int k0i = j0 + 4 * g + e;
            int k1i = k0i + 16;
            float v0 = (k0i <= q && k0i >= q - MEM) ? s0[e] * 0.125f : NEG_INF;
            float v1 = (k1i <= q && k1i >= q - MEM) ? s1[e] * 0.125f : NEG_INF;
            s0[e] = v0; s1[e] = v1;
            mt = fmaxf(mt, fmaxf(v0, v1));
        }
        mt = fmaxf(mt, __shfl_xor(mt, 16, 64));
        mt = fmaxf(mt, __shfl_xor(mt, 32, 64));

        // T13 defer-max: rescale only when the tile max grew past m_run + 8.
        if (!__all(mt <= m_run + 8.f)) {
            const float mnew = fmaxf(m_run, mt);
            const float corr = __expf(m_run - mnew);   // lane-local (q = c); first tile: 0
#pragma unroll
            for (int cb = 0; cb < 4; ++cb) {
                o[cb][0] *= corr; o[cb][1] *= corr; o[cb][2] *= corr; o[cb][3] *= corr;
            }
            l_run *= corr;
            m_run = mnew;
        }

        float ps = 0.f;
        bf16x8 pav;
#pragma unroll
        for (int e = 0; e < 4; ++e) {
            float e0 = __expf(s0[e] - m_run);
            float e1 = __expf(s1[e] - m_run);
            ps += e0 + e1;
            pav[e]     = (bf16)e0;
            pav[4 + e] = (bf16)e1;
        }
        ps += __shfl_xor(ps, 16, 64);
        ps += __shfl_xor(ps, 32, 64);
        l_run += ps;

        const int jrel = j0 - wlo;
        const int c8a = (jrel + 4 * g) >> 2;
        const int c8b = (c8a + 4 > 95) ? 95 : (c8a + 4);
#pragma unroll
        for (int cb = 0; cb < 4; ++cb) {
            const int d = cb * 16 + c;
            const int xx = d & 14;
            const bf16* vrow = vtl + d * 384;
            bf16x4 va  = *reinterpret_cast<const bf16x4*>(vrow + ((c8a ^ xx) << 2));
            bf16x4 vb2 = *reinterpret_cast<const bf16x4*>(vrow + ((c8b ^ xx) << 2));
            bf16x8 vf = { va[0], va[1], va[2], va[3], vb2[0], vb2[1], vb2[2], vb2[3] };
            o[cb] = __builtin_amdgcn_mfma_f32_16x16x32_bf16(vf, pav, o[cb], 0, 0, 0);
        }

        if (more) { kc00 = kn00; kc01 = kn01; kc10 = kn10; kc11 = kn11; }
    }
#undef LOAD_K

    const float linv = 1.0f / l_run;
    bf16* yr = y + (size_t)(b * T_SEQ + q) * CDIM + h * 64 + 4 * g;
#pragma unroll
    for (int cb = 0; cb < 4; ++cb) {
        bf16x4 ov = { (bf16)(o[cb][0] * linv), (bf16)(o[cb][1] * linv),
                      (bf16)(o[cb][2] * linv), (bf16)(o[cb][3] * linv) };
        *reinterpret_cast<bf16x4*>(yr + cb * 16) = ov;
    }
}

// ---------------- launch ----------------
extern "C" void kernel_launch(void* const* d_in, const int* in_sizes, int n_in,
                              void* d_out, int out_size, void* d_ws, size_t ws_size,
                              hipStream_t stream) {
    const float* x      = (const float*)d_in[0];
    const float* W_attn = (const float*)d_in[1];
    const float* W_proj = (const float*)d_in[2];
    float* out = (float*)d_out;

    char* ws = (char*)d_ws;
    bf16* xb   = (bf16*)(ws);                  //  4096x1024 bf16 =  8 MiB
    bf16* WaT  = (bf16*)(ws + 8388608);        //  3072x1024 bf16 =  6 MiB
    bf16* WpT  = (bf16*)(ws + 14680064);       //  1024x1024 bf16 =  2 MiB
    bf16* qkv  = (bf16*)(ws + 16777216);       //  4096x3072 bf16 = 24 MiB (V third unused)
    bf16* yatt = (bf16*)(ws + 41943040);       //  4096x1024 bf16 =  8 MiB
    bf16* Vt   = (bf16*)(ws + 50331648);       //  2x16x64x2048 bf16 = 8 MiB

    prep_kernel<<<3072, 256, 0, stream>>>(x, W_attn, W_proj, xb, WaT, WpT);
    gemm256_kernel<<<512, 512, 0, stream>>>(xb, WaT, qkv, Vt, 4096, 3072, 1024);
    attn_kernel<<<512, 512, 0, stream>>>(qkv, Vt, yatt);
    proj_kernel<<<dim3(16, 32), 256, 0, stream>>>(yatt, WpT, out, 4096, 1024, 1024);
}

// Round 23
// 87.959 us; speedup vs baseline: 1.0025x; 1.0015x over previous
//
#include <hip/hip_runtime.h>

typedef __bf16 bf16;
typedef __bf16 bf16x4 __attribute__((ext_vector_type(4)));
typedef __bf16 bf16x8 __attribute__((ext_vector_type(8)));
typedef float f32x4 __attribute__((ext_vector_type(4)));

#define T_SEQ 2048
#define CDIM  1024
#define QKV_LD 3072
#define MEM   256

// global -> LDS direct DMA, 16B per lane. LDS dest is wave-uniform base + lane*16B.
#define GLOAD_LDS16(gp, lp) __builtin_amdgcn_global_load_lds( \
    (const __attribute__((address_space(1))) unsigned int*)(gp), \
    (__attribute__((address_space(3))) unsigned int*)(lp), 16, 0, 0)

#define BAR() do { __builtin_amdgcn_s_barrier(); asm volatile("" ::: "memory"); } while (0)

// ------------- fused prep (frozen R19) -------------
__global__ __launch_bounds__(256) void prep_kernel(const float* __restrict__ x,
                                                   const float* __restrict__ Wa,
                                                   const float* __restrict__ Wp,
                                                   bf16* __restrict__ xb,
                                                   bf16* __restrict__ WaT,
                                                   bf16* __restrict__ WpT) {
    const int bid = blockIdx.x;
    if (bid < 2048) {
        int i = bid * 256 + threadIdx.x;            // 8-elem chunk index
        float4 v0 = reinterpret_cast<const float4*>(x)[i * 2];
        float4 v1 = reinterpret_cast<const float4*>(x)[i * 2 + 1];
        bf16x8 o = { (bf16)v0.x, (bf16)v0.y, (bf16)v0.z, (bf16)v0.w,
                     (bf16)v1.x, (bf16)v1.y, (bf16)v1.z, (bf16)v1.w };
        reinterpret_cast<bf16x8*>(xb)[i] = o;
        return;
    }
    const float* W; bf16* Wt; int N, bx, by;
    if (bid < 2816) { W = Wa; Wt = WaT; N = 3072; int idx = bid - 2048; bx = idx % 48; by = idx / 48; }
    else            { W = Wp; Wt = WpT; N = 1024; int idx = bid - 2816; bx = idx % 16; by = idx / 16; }
    __shared__ float tile[64][65];
    const int n0 = bx * 64;
    const int k0 = by * 64;
    const int t  = threadIdx.x;
    const int tr = t >> 4;
    const int tc = (t & 15) * 4;
#pragma unroll
    for (int it = 0; it < 4; ++it) {
        int r = it * 16 + tr;
        float4 v = *reinterpret_cast<const float4*>(&W[(size_t)(k0 + r) * N + n0 + tc]);
        tile[r][tc + 0] = v.x; tile[r][tc + 1] = v.y;
        tile[r][tc + 2] = v.z; tile[r][tc + 3] = v.w;
    }
    __syncthreads();
#pragma unroll
    for (int it = 0; it < 4; ++it) {
        int n = it * 16 + tr;
        bf16x4 o;
#pragma unroll
        for (int j = 0; j < 4; ++j) o[j] = (bf16)tile[tc + j][n];
        *reinterpret_cast<bf16x4*>(&Wt[(size_t)(n0 + n) * 1024 + k0 + tc]) = o;
    }
}

// ------------- 128x192 GEMM (exact R16 structure — frozen, best verified) -------------
__global__ __launch_bounds__(512, 4) void gemm256_kernel(const bf16* __restrict__ A,
                                                         const bf16* __restrict__ Bt,
                                                         bf16* __restrict__ Cb,
                                                         bf16* __restrict__ Vt,
                                                         int M, int N, int K) {
    __shared__ bf16 lds[40960];          // 80 KiB: [0,16384) = A dbuf, [16384,40960) = B dbuf
#define SMA(bi, row) (lds + (((bi) * 128 + (row)) << 6))
#define SMB(bi, row) (lds + 16384 + (((bi) * 192 + (row)) << 6))
    const int t    = threadIdx.x;
    const int lane = t & 63;
    const int w    = t >> 6;
    const int wm   = (w >> 2) * 64;
    const int wn   = (w & 3) * 48;
    const int g    = lane >> 4;
    const int r    = lane & 15;

    const int xcd   = blockIdx.x & 7;
    const int local = blockIdx.x >> 3;
    const int mt = (xcd >> 1) * 8 + (local >> 3);
    const int nt = (xcd & 1) * 8 + (local & 7);
    const int m0 = mt * 128;
    const int n0 = nt * 192;

    const bf16* Ab = A  + (size_t)m0 * K;
    const bf16* Bb = Bt + (size_t)n0 * K;
    const int NT = K >> 6;

#define STAGE_A(bi, u, kt) do { \
        const bf16* _s = Ab + (size_t)((u) * 64 + w * 8 + (lane >> 3)) * K \
                         + (kt) * 64 + ((lane & 7) ^ (lane >> 3)) * 8; \
        GLOAD_LDS16(_s, SMA(bi, (u) * 64 + w * 8)); \
    } while (0)
#define STAGE_B(bi, u, kt) do { \
        const bf16* _s = Bb + (size_t)((u) * 64 + w * 8 + (lane >> 3)) * K \
                         + (kt) * 64 + ((lane & 7) ^ (lane >> 3)) * 8; \
        GLOAD_LDS16(_s, SMB(bi, (u) * 64 + w * 8)); \
    } while (0)

    const int ch0 = ((g     ) ^ (r & 7)) * 8;
    const int ch1 = ((g ^ 4) ^ (r & 7)) * 8;

    const f32x4 zero4 = {0.f, 0.f, 0.f, 0.f};
    f32x4 acc[4][3];
#pragma unroll
    for (int i = 0; i < 4; ++i)
#pragma unroll
        for (int j = 0; j < 3; ++j) acc[i][j] = zero4;

    bf16x8 afr[4][2], bfrA[2][2], bfrB[1][2];

#define MGRP(BF, FNB, NF) do { \
    __builtin_amdgcn_s_setprio(1); \
    _Pragma("unroll") \
    for (int fm2 = 0; fm2 < 4; ++fm2) \
    _Pragma("unroll") \
    for (int fn2 = 0; fn2 < (NF); ++fn2) \
    _Pragma("unroll") \
    for (int kh = 0; kh < 2; ++kh) \
        acc[fm2][(FNB)+fn2] = __builtin_amdgcn_mfma_f32_16x16x32_bf16( \
            afr[fm2][kh], BF[fn2][kh], acc[fm2][(FNB)+fn2], 0, 0, 0); \
    __builtin_amdgcn_s_setprio(0); } while (0)

    STAGE_A(0, 0, 0); STAGE_A(0, 1, 0);
    STAGE_B(0, 0, 0); STAGE_B(0, 1, 0); STAGE_B(0, 2, 0);
    asm volatile("s_waitcnt vmcnt(0)" ::: "memory");
    __builtin_amdgcn_sched_barrier(0);
    BAR();

    for (int kt = 0; kt < NT; ++kt) {
        const int cur = kt & 1, nxt = cur ^ 1;
#pragma unroll
        for (int i = 0; i < 4; ++i) {
            afr[i][0] = *reinterpret_cast<const bf16x8*>(SMA(cur, wm + i * 16 + r) + ch0);
            afr[i][1] = *reinterpret_cast<const bf16x8*>(SMA(cur, wm + i * 16 + r) + ch1);
        }
#pragma unroll
        for (int fn = 0; fn < 2; ++fn) {
            bfrA[fn][0] = *reinterpret_cast<const bf16x8*>(SMB(cur, wn + fn * 16 + r) + ch0);
            bfrA[fn][1] = *reinterpret_cast<const bf16x8*>(SMB(cur, wn + fn * 16 + r) + ch1);
        }
        bfrB[0][0] = *reinterpret_cast<const bf16x8*>(SMB(cur, wn + 32 + r) + ch0);
        bfrB[0][1] = *reinterpret_cast<const bf16x8*>(SMB(cur, wn + 32 + r) + ch1);

        if (kt + 1 < NT) {
            STAGE_A(nxt, 0, kt + 1); STAGE_A(nxt, 1, kt + 1);
            STAGE_B(nxt, 0, kt + 1); STAGE_B(nxt, 1, kt + 1); STAGE_B(nxt, 2, kt + 1);
        }

        MGRP(bfrA, 0, 2);
        MGRP(bfrB, 2, 1);

        asm volatile("s_waitcnt vmcnt(0)" ::: "memory");
        __builtin_amdgcn_sched_barrier(0);
        BAR();
    }

    bf16* stage = lds + (size_t)w * (48 * 72);
#pragma unroll
    for (int fm = 0; fm < 4; ++fm)
#pragma unroll
        for (int fn = 0; fn < 3; ++fn) {
            const int col  = n0 + wn + fn * 16 + r;
            const int row0 = m0 + wm + fm * 16 + g * 4;
            if (col < 2 * CDIM) {
#pragma unroll
                for (int e = 0; e < 4; ++e)
                    Cb[(size_t)(row0 + e) * N + col] = (bf16)acc[fm][fn][e];
            } else {
                const int dl = fn * 16 + r;
                const int tl = fm * 16 + g * 4;
#pragma unroll
                for (int e = 0; e < 4; ++e)
                    stage[dl * 72 + tl + e] = (bf16)acc[fm][fn][e];
            }
        }
    if (n0 + wn + 47 >= 2 * CDIM) {
        if (lane < 48 && (n0 + wn + lane) >= 2 * CDIM) {
            const int hd = n0 + wn + lane - 2 * CDIM;
            const int bb = m0 >> 11;
            const int tt = (m0 & (T_SEQ - 1)) + wm;
            bf16* dst = &Vt[((size_t)(bb * 16 + (hd >> 6)) * 64 + (hd & 63)) * T_SEQ + tt];
            const bf16* srcl = stage + lane * 72;
#pragma unroll
            for (int jj = 0; jj < 8; ++jj)
                reinterpret_cast<bf16x8*>(dst)[jj] = reinterpret_cast<const bf16x8*>(srcl)[jj];
        }
    }
#undef STAGE_A
#undef STAGE_B
#undef MGRP
#undef SMA
#undef SMB
}

// ------------- proj GEMM: race-free t+1 double-buffer (frozen R20) -------------
__global__ __launch_bounds__(256) void proj_kernel(const bf16* __restrict__ A,
                                                   const bf16* __restrict__ Bt,
                                                   float* __restrict__ Cf,
                                                   int M, int N, int K) {
    __shared__ bf16 As[2][128 * 32];
    __shared__ bf16 Bs[2][64 * 32];
    const int t    = threadIdx.x;
    const int lane = t & 63;
    const int w    = t >> 6;
    const int wm   = (w >> 1) * 64;
    const int wn   = (w & 1) * 32;
    const int g    = lane >> 4;
    const int r    = lane & 15;
    const int m0   = blockIdx.y * 128;
    const int n0   = blockIdx.x * 64;

    const bf16* Ab = A  + (size_t)m0 * K;
    const bf16* Bb = Bt + (size_t)n0 * K;
    const bf16* Ag0 = Ab + (size_t)(w * 32 + (lane >> 2)) * K + (lane & 3) * 8;
    const bf16* Ag1 = Ab + (size_t)(w * 32 + 16 + (lane >> 2)) * K + (lane & 3) * 8;
    const bf16* Bg0 = Bb + (size_t)(w * 16 + (lane >> 2)) * K + (lane & 3) * 8;

    const int aoff0 = (w * 32) * 32;
    const int aoff1 = (w * 32 + 16) * 32;
    const int boff0 = (w * 16) * 32;

    const f32x4 zero4 = {0.f, 0.f, 0.f, 0.f};
    f32x4 acc[4][2];
#pragma unroll
    for (int i = 0; i < 4; ++i)
#pragma unroll
        for (int j = 0; j < 2; ++j) acc[i][j] = zero4;

    const int NT = K >> 5;               // K-steps of 32

    GLOAD_LDS16(Ag0, &As[0][aoff0]);
    GLOAD_LDS16(Ag1, &As[0][aoff1]);
    GLOAD_LDS16(Bg0, &Bs[0][boff0]);
    asm volatile("s_waitcnt vmcnt(0)" ::: "memory");
    __builtin_amdgcn_sched_barrier(0);
    BAR();

    for (int kt = 0; kt < NT; ++kt) {
        const int cur = kt & 1, nxt = cur ^ 1;
        bf16x8 af[4], bfr[2];
#pragma unroll
        for (int i = 0; i < 4; ++i)
            af[i]  = *reinterpret_cast<const bf16x8*>(&As[cur][(wm + i * 16 + r) * 32 + g * 8]);
#pragma unroll
        for (int j = 0; j < 2; ++j)
            bfr[j] = *reinterpret_cast<const bf16x8*>(&Bs[cur][(wn + j * 16 + r) * 32 + g * 8]);

        if (kt + 1 < NT) {
            const int k1 = (kt + 1) * 32;
            GLOAD_LDS16(Ag0 + k1, &As[nxt][aoff0]);
            GLOAD_LDS16(Ag1 + k1, &As[nxt][aoff1]);
            GLOAD_LDS16(Bg0 + k1, &Bs[nxt][boff0]);
        }

#pragma unroll
        for (int i = 0; i < 4; ++i)
#pragma unroll
            for (int j = 0; j < 2; ++j)
                acc[i][j] = __builtin_amdgcn_mfma_f32_16x16x32_bf16(af[i], bfr[j], acc[i][j], 0, 0, 0);

        asm volatile("s_waitcnt vmcnt(0)" ::: "memory");
        __builtin_amdgcn_sched_barrier(0);
        BAR();
    }

#pragma unroll
    for (int i = 0; i < 4; ++i)
#pragma unroll
        for (int j = 0; j < 2; ++j)
#pragma unroll
            for (int e = 0; e < 4; ++e) {
                int row = m0 + wm + i * 16 + g * 4 + e;
                int col = n0 + wn + j * 16 + r;
                Cf[(size_t)row * N + col] = acc[i][j][e];
            }
}

// ------------- banded flash attention v5 + T13 defer-max (frozen R21) -------------
__global__ __launch_bounds__(512) void attn_kernel(const bf16* __restrict__ qkv,
                                                   const bf16* __restrict__ Vt,
                                                   bf16* __restrict__ y) {
    __shared__ bf16 vtl[64 * 384];
    const int bid  = blockIdx.x;
    const int bh   = bid >> 4;
    const int qblk = bid & 15;
    const int b = bh >> 4, h = bh & 15;
    const int qb0 = qblk * 128;
    const int wlo = qb0 - 256;
    const int wv   = threadIdx.x >> 6;
    const int lane = threadIdx.x & 63;
    const int g = lane >> 4, c = lane & 15;
    const int q0 = qb0 + wv * 16;
    const int q = q0 + c;
    const float NEG_INF = -__builtin_inff();

    const bf16* base = qkv + (size_t)b * T_SEQ * QKV_LD;
    const bf16* Qb = base + h * 64;
    const bf16* Kb = base + CDIM + h * 64;
    const bf16* Vtb = Vt + (size_t)(b * 16 + h) * 64 * T_SEQ;

#pragma unroll
    for (int i = 0; i < 6; ++i) {
        const int Lb = (wv * 6 + i) * 1024 + lane * 16;
        const int d   = Lb / 768;
        const int c16 = (Lb % 768) >> 4;
        int koff = ((2 * c16) ^ (d & 14)) << 2;
        int gk = wlo + koff;
        gk = gk < 0 ? 0 : gk;
        GLOAD_LDS16(Vtb + (size_t)d * T_SEQ + gk, vtl + (wv * 6 + i) * 512);
    }

    const bf16x8 qf0 = *reinterpret_cast<const bf16x8*>(Qb + (size_t)q * QKV_LD + g * 8);
    const bf16x8 qf1 = *reinterpret_cast<const bf16x8*>(Qb + (size_t)q * QKV_LD + 32 + g * 8);

    __syncthreads();

    const f32x4 zero4 = {0.f, 0.f, 0.f, 0.f};
    f32x4 o[4];
#pragma unroll
    for (int cb = 0; cb < 4; ++cb) o[cb] = zero4;
    float m_run = NEG_INF, l_run = 0.f;

#define LOAD_K(J0, K00, K01, K10, K11) do { \
        const int _kr0 = (J0) + c; \
        int _kr1 = (J0) + 16 + c; _kr1 = _kr1 < T_SEQ ? _kr1 : T_SEQ - 1; \
        K00 = *reinterpret_cast<const bf16x8*>(Kb + (size_t)_kr0 * QKV_LD + g * 8); \
        K01 = *reinterpret_cast<const bf16x8*>(Kb + (size_t)_kr0 * QKV_LD + 32 + g * 8); \
        K10 = *reinterpret_cast<const bf16x8*>(Kb + (size_t)_kr1 * QKV_LD + g * 8); \
        K11 = *reinterpret_cast<const bf16x8*>(Kb + (size_t)_kr1 * QKV_LD + 32 + g * 8); \
    } while (0)

    const int jstart = (q0 - MEM > 0) ? (q0 - MEM) : 0;
    bf16x8 kc00, kc01, kc10, kc11;
    LOAD_K(jstart, kc00, kc01, kc10, kc11);

    for (int j0 = jstart; j0 < q0 + 16; j0 += 32) {
        bf16x8 kn00, kn01, kn10, kn11;
        const bool more = (j0 + 32 < q0 + 16);
        if (more) LOAD_K(j0 + 32, kn00, kn01, kn10, kn11);

        f32x4 s0 = __builtin_amdgcn_mfma_f32_16x16x32_bf16(kc00, qf0, zero4, 0, 0, 0);
        s0 = __builtin_amdgcn_mfma_f32_16x16x32_bf16(kc01, qf1, s0, 0, 0, 0);
        f32x4 s1 = __builtin_amdgcn_mfma_f32_16x16x32_bf16(kc10, qf0, zero4, 0, 0, 0);
        s1 = __builtin_amdgcn_mfma_f32_16x16x32_bf16(kc11, qf1, s1, 0, 0, 0);

        float mt = NEG_INF;
#pragma unroll
        for (int e = 0; e < 4; ++e) {
            int k0i = j0 + 4 * g + e;
            int k1i = k0i + 16;
            float v0 = (k0i <= q && k0i >= q - MEM) ? s0[e] * 0.125f : NEG_INF;
            float v1 = (k1i <= q && k1i >= q - MEM) ? s1[e] * 0.125f : NEG_INF;
            s0[e] = v0; s1[e] = v1;
            mt = fmaxf(mt, fmaxf(v0, v1));
        }
        mt = fmaxf(mt, __shfl_xor(mt, 16, 64));
        mt = fmaxf(mt, __shfl_xor(mt, 32, 64));

        // T13 defer-max: rescale only when the tile max grew past m_run + 8.
        if (!__all(mt <= m_run + 8.f)) {
            const float mnew = fmaxf(m_run, mt);
            const float corr = __expf(m_run - mnew);   // lane-local (q = c); first tile: 0
#pragma unroll
            for (int cb = 0; cb < 4; ++cb) {
                o[cb][0] *= corr; o[cb][1] *= corr; o[cb][2] *= corr; o[cb][3] *= corr;
            }
            l_run *= corr;
            m_run = mnew;
        }

        float ps = 0.f;
        bf16x8 pav;
#pragma unroll
        for (int e = 0; e < 4; ++e) {
            float e0 = __expf(s0[e] - m_run);
            float e1 = __expf(s1[e] - m_run);
            ps += e0 + e1;
            pav[e]     = (bf16)e0;
            pav[4 + e] = (bf16)e1;
        }
        ps += __shfl_xor(ps, 16, 64);
        ps += __shfl_xor(ps, 32, 64);
        l_run += ps;

        const int jrel = j0 - wlo;
        const int c8a = (jrel + 4 * g) >> 2;
        const int c8b = (c8a + 4 > 95) ? 95 : (c8a + 4);
#pragma unroll
        for (int cb = 0; cb < 4; ++cb) {
            const int d = cb * 16 + c;
            const int xx = d & 14;
            const bf16* vrow = vtl + d * 384;
            bf16x4 va  = *reinterpret_cast<const bf16x4*>(vrow + ((c8a ^ xx) << 2));
            bf16x4 vb2 = *reinterpret_cast<const bf16x4*>(vrow + ((c8b ^ xx) << 2));
            bf16x8 vf = { va[0], va[1], va[2], va[3], vb2[0], vb2[1], vb2[2], vb2[3] };
            o[cb] = __builtin_amdgcn_mfma_f32_16x16x32_bf16(vf, pav, o[cb], 0, 0, 0);
        }

        if (more) { kc00 = kn00; kc01 = kn01; kc10 = kn10; kc11 = kn11; }
    }
#undef LOAD_K

    const float linv = 1.0f / l_run;
    bf16* yr = y + (size_t)(b * T_SEQ + q) * CDIM + h * 64 + 4 * g;
#pragma unroll
    for (int cb = 0; cb < 4; ++cb) {
        bf16x4 ov = { (bf16)(o[cb][0] * linv), (bf16)(o[cb][1] * linv),
                      (bf16)(o[cb][2] * linv), (bf16)(o[cb][3] * linv) };
        *reinterpret_cast<bf16x4*>(yr + cb * 16) = ov;
    }
}

// ---------------- launch ----------------
extern "C" void kernel_launch(void* const* d_in, const int* in_sizes, int n_in,
                              void* d_out, int out_size, void* d_ws, size_t ws_size,
                              hipStream_t stream) {
    const float* x      = (const float*)d_in[0];
    const float* W_attn = (const float*)d_in[1];
    const float* W_proj = (const float*)d_in[2];
    float* out = (float*)d_out;

    char* ws = (char*)d_ws;
    bf16* xb   = (bf16*)(ws);                  //  4096x1024 bf16 =  8 MiB
    bf16* WaT  = (bf16*)(ws + 8388608);        //  3072x1024 bf16 =  6 MiB
    bf16* WpT  = (bf16*)(ws + 14680064);       //  1024x1024 bf16 =  2 MiB
    bf16* qkv  = (bf16*)(ws + 16777216);       //  4096x3072 bf16 = 24 MiB (V third unused)
    bf16* yatt = (bf16*)(ws + 41943040);       //  4096x1024 bf16 =  8 MiB
    bf16* Vt   = (bf16*)(ws + 50331648);       //  2x16x64x2048 bf16 = 8 MiB

    prep_kernel<<<3072, 256, 0, stream>>>(x, W_attn, W_proj, xb, WaT, WpT);
    gemm256_kernel<<<512, 512, 0, stream>>>(xb, WaT, qkv, Vt, 4096, 3072, 1024);
    attn_kernel<<<512, 512, 0, stream>>>(qkv, Vt, yatt);
    proj_kernel<<<dim3(16, 32), 256, 0, stream>>>(yatt, WpT, out, 4096, 1024, 1024);
}